// Round 9
// baseline (300.105 us; speedup 1.0000x reference)
//
#include <hip/hip_runtime.h>

typedef _Float16 h2 __attribute__((ext_vector_type(2)));
typedef _Float16 h8 __attribute__((ext_vector_type(8)));

#define BB 256
#define II 1152
#define QQ 8
#define JJ 10
#define PP 16

#define BT 8             // b per block (128 threads = 8 b-lanes x 16 p-lanes)
#define IT 8             // i per block (grid 4608 for TLP)
#define NBT (BB / BT)    // 32
#define NIT (II / IT)    // 144
#define XRH 72           // halfs per b-row of staged x (64 + 8 pad)

#define NW (JJ * II * PP * QQ)   // 1474560
#define NX (BB * II * QQ)        // 2359296
#define NS (BB * JJ * PP)        // 40960
#define LOG2E 1.4426950408889634f

// ---------------------------------------------------------------------------
// 16-lane row sum via DPP (VALU pipe only).
// ---------------------------------------------------------------------------
template <int CTRL>
__device__ __forceinline__ float dpp_add(float v) {
    int s = __builtin_bit_cast(int, v);
    int t = __builtin_amdgcn_update_dpp(0, s, CTRL, 0xF, 0xF, true);
    return v + __builtin_bit_cast(float, t);
}
__device__ __forceinline__ float row_sum16(float v) {
    v = dpp_add<0xB1>(v);   // xor1
    v = dpp_add<0x4E>(v);   // xor2
    v = dpp_add<0x124>(v);  // row_ror:4
    v = dpp_add<0x128>(v);  // row_ror:8
    return v;
}

// 8-element f16 dot with fp32 accumulate: 4 x v_dot2_f32_f16.
__device__ __forceinline__ float dot8(h8 w, h8 x) {
    h2 w0 = __builtin_shufflevector(w, w, 0, 1), w1 = __builtin_shufflevector(w, w, 2, 3);
    h2 w2 = __builtin_shufflevector(w, w, 4, 5), w3 = __builtin_shufflevector(w, w, 6, 7);
    h2 x0 = __builtin_shufflevector(x, x, 0, 1), x1 = __builtin_shufflevector(x, x, 2, 3);
    h2 x2 = __builtin_shufflevector(x, x, 4, 5), x3 = __builtin_shufflevector(x, x, 6, 7);
    float acc = __builtin_amdgcn_fdot2(w0, x0, 0.0f, false);
    acc = __builtin_amdgcn_fdot2(w1, x1, acc, false);
    acc = __builtin_amdgcn_fdot2(w2, x2, acc, false);
    acc = __builtin_amdgcn_fdot2(w3, x3, acc, false);
    return acc;
}

// ---------------------------------------------------------------------------
// prep (vectorized): W,X fp32 -> f16; zero S0/S1/S2.
// ---------------------------------------------------------------------------
__global__ __launch_bounds__(256) void prep_kernel(
    const float* __restrict__ X, const float* __restrict__ W,
    _Float16* __restrict__ Xh, _Float16* __restrict__ Wh,
    float* __restrict__ S)   // 3*NS floats
{
    const int g = blockIdx.x * 256 + threadIdx.x;
    const int stride = gridDim.x * 256;
    typedef _Float16 h4 __attribute__((ext_vector_type(4)));
    for (int k = g; k < NW / 4; k += stride) {
        const float4 f = ((const float4*)W)[k];
        h4 o = { (_Float16)f.x, (_Float16)f.y, (_Float16)f.z, (_Float16)f.w };
        ((h4*)Wh)[k] = o;
    }
    for (int k = g; k < NX / 4; k += stride) {
        const float4 f = ((const float4*)X)[k];
        h4 o = { (_Float16)f.x, (_Float16)f.y, (_Float16)f.z, (_Float16)f.w };
        ((h4*)Xh)[k] = o;
    }
    const float4 z = {0.f, 0.f, 0.f, 0.f};
    for (int k = g; k < 3 * NS / 4; k += stride) ((float4*)S)[k] = z;
}

// ---------------------------------------------------------------------------
// Fused routing pass (f16, software-pipelined W loads).
// Thread = (b_l, p). Register double-buffer: W fragments for iteration i+1
// are issued before computing iteration i (hides L2 latency behind ~150 VALU).
// Block prologue (R>0): vv[j] = squash(Sprev)[p] * log2e via DPP;
// R==1,it==0 persists v0; R==2 adds v0 (cumulative logits without BL tensor).
// ---------------------------------------------------------------------------
template <int R>
__global__ __launch_bounds__(128, 4) void pass_kernel(
    const _Float16* __restrict__ Xh,  // [B][I][Q] f16
    const _Float16* __restrict__ Wh,  // [J][I][P][Q] f16
    const float* __restrict__ Sprev,  // [B][J][P] (R>0)
    float* __restrict__ V0,           // [B][J][P] v0 (R1 writes it==0, R2 reads)
    float* __restrict__ Sout)         // [B][J][P] pre-zeroed accumulator
{
    __shared__ _Float16 xs[BT * XRH];  // 1152 B

    const int bt = blockIdx.x & (NBT - 1);
    const int it = blockIdx.x >> 5;
    const int b0 = bt * BT;
    const int i0 = it * IT;
    const int tid = threadIdx.x;

    {
        const int b_l = tid >> 4;
        const int r   = tid & 15;
        *(uint2*)(xs + b_l * XRH + r * 4) =
            *(const uint2*)(Xh + ((size_t)(b0 + b_l) * II + i0) * QQ + r * 4);
    }
    __syncthreads();

    const int b_l = tid >> 4;
    const int p   = tid & 15;
    const int b   = b0 + b_l;

    // base pointer for this thread's W fragments (j-stride = II*PP*QQ halfs)
    const _Float16* wbase = Wh + (((size_t)i0) * PP + p) * QQ;

    float vv[JJ];
    if (R > 0) {
#pragma unroll
        for (int j = 0; j < JJ; ++j) {
            const float sp = Sprev[((size_t)b * JJ + j) * PP + p];
            const float n2 = row_sum16(sp * sp);
            const float scale = n2 * __builtin_amdgcn_rcpf(1.0f + n2)
                                   * __builtin_amdgcn_rsqf(n2 + 1e-7f);
            float v = sp * scale;
            if (R == 1) {
                if (it == 0) V0[((size_t)b * JJ + j) * PP + p] = v;
            } else {
                v += V0[((size_t)b * JJ + j) * PP + p];
            }
            vv[j] = v * LOG2E;
        }
    }

    float sacc[JJ];
#pragma unroll
    for (int j = 0; j < JJ; ++j) sacc[j] = 0.0f;

    // ---- software pipeline: wbuf[cur] computes while wbuf[nxt] loads
    h8 wbuf[2][JJ];
#pragma unroll
    for (int j = 0; j < JJ; ++j)
        wbuf[0][j] = *(const h8*)(wbase + (size_t)j * (II * PP * QQ));

#pragma unroll
    for (int i = 0; i < IT; ++i) {
        const int cur = i & 1;
        if (i + 1 < IT) {
#pragma unroll
            for (int j = 0; j < JJ; ++j)
                wbuf[cur ^ 1][j] =
                    *(const h8*)(wbase + (size_t)j * (II * PP * QQ) + (i + 1) * (PP * QQ));
        }

        const h8 x8 = *(const h8*)(xs + b_l * XRH + i * QQ);

        float h[JJ];
#pragma unroll
        for (int j = 0; j < JJ; ++j) h[j] = dot8(wbuf[cur][j], x8);

        if (R == 0) {
#pragma unroll
            for (int j = 0; j < JJ; ++j) sacc[j] += h[j];
        } else {
            float e[JJ];
#pragma unroll
            for (int j = 0; j < JJ; ++j) {
                const float bj = row_sum16(vv[j] * h[j]);
                e[j] = exp2f(bj);
            }
            // tree sum (depth 4) instead of serial chain
            float s01 = e[0] + e[1], s23 = e[2] + e[3], s45 = e[4] + e[5],
                  s67 = e[6] + e[7], s89 = e[8] + e[9];
            float t0 = s01 + s23, t1 = s45 + s67;
            const float sum = (t0 + t1) + s89;
            const float inv = __builtin_amdgcn_rcpf(sum);
#pragma unroll
            for (int j = 0; j < JJ; ++j) sacc[j] += (e[j] * inv) * h[j];
        }
    }

#pragma unroll
    for (int j = 0; j < JJ; ++j)
        atomicAdd(&Sout[((size_t)b * JJ + j) * PP + p],
                  (R == 0) ? 0.1f * sacc[j] : sacc[j]);
}

// ---------------------------------------------------------------------------
// final output squash (fp32 precise)
// ---------------------------------------------------------------------------
__global__ __launch_bounds__(256) void squash_out_kernel(const float* __restrict__ S,
                                                         float* __restrict__ V)
{
    const int idx = blockIdx.x * blockDim.x + threadIdx.x;  // (b*J + j)
    if (idx >= BB * JJ) return;
    const float4* sp = (const float4*)(S + idx * PP);
    float4 a = sp[0], b4 = sp[1], c4 = sp[2], d4 = sp[3];
    float s2 = a.x * a.x + a.y * a.y + a.z * a.z + a.w * a.w +
               b4.x * b4.x + b4.y * b4.y + b4.z * b4.z + b4.w * b4.w +
               c4.x * c4.x + c4.y * c4.y + c4.z * c4.z + c4.w * c4.w +
               d4.x * d4.x + d4.y * d4.y + d4.z * d4.z + d4.w * d4.w;
    const float scale = s2 / (1.0f + s2) / sqrtf(s2 + 1e-7f);
    a.x *= scale; a.y *= scale; a.z *= scale; a.w *= scale;
    b4.x *= scale; b4.y *= scale; b4.z *= scale; b4.w *= scale;
    c4.x *= scale; c4.y *= scale; c4.z *= scale; c4.w *= scale;
    d4.x *= scale; d4.y *= scale; d4.z *= scale; d4.w *= scale;
    float4* vp = (float4*)(V + idx * PP);
    vp[0] = a; vp[1] = b4; vp[2] = c4; vp[3] = d4;
}

extern "C" void kernel_launch(void* const* d_in, const int* in_sizes, int n_in,
                              void* d_out, int out_size, void* d_ws, size_t ws_size,
                              hipStream_t stream)
{
    const float* X = (const float*)d_in[0];  // [256][1152][8]
    const float* W = (const float*)d_in[1];  // [10][1152][16][8]
    float* out = (float*)d_out;              // [256][10][16]

    _Float16* Xh = (_Float16*)d_ws;          // NX halfs
    _Float16* Wh = Xh + NX;                  // NW halfs
    float* S0 = (float*)(Wh + NW);           // NS floats
    float* S1 = S0 + NS;
    float* S2 = S1 + NS;
    float* v0 = S2 + NS;                     // NS floats; total ~8.3 MB

    const int grid = NBT * NIT;  // 4608 blocks of 128 threads

    prep_kernel<<<1024, 256, 0, stream>>>(X, W, Xh, Wh, S0);
    pass_kernel<0><<<grid, 128, 0, stream>>>(Xh, Wh, nullptr, nullptr, S0);
    pass_kernel<1><<<grid, 128, 0, stream>>>(Xh, Wh, S0, v0, S1);
    pass_kernel<2><<<grid, 128, 0, stream>>>(Xh, Wh, S1, v0, S2);
    squash_out_kernel<<<10, 256, 0, stream>>>(S2, out);
}

// Round 10
// 155.930 us; speedup vs baseline: 1.9246x; 1.9246x over previous
//
#include <hip/hip_runtime.h>

typedef _Float16 h2 __attribute__((ext_vector_type(2)));
typedef _Float16 h8 __attribute__((ext_vector_type(8)));

#define BB 256
#define II 1152
#define QQ 8
#define JJ 10
#define PP 16

#define BT 16            // b per block (256 threads = 16 b-groups x 16 p-lanes)
#define IT 8             // i per block
#define NBT (BB / BT)    // 16
#define NIT (II / IT)    // 144
#define XRH 72           // halfs per staged-x b-row (64 + 8 pad -> bank-shifted)
#define WTILE (IT * PP * QQ)     // 1024 halfs per j in the LDS W-tile

#define NW (JJ * II * PP * QQ)   // 1474560
#define NX (BB * II * QQ)        // 2359296
#define NS (BB * JJ * PP)        // 40960
#define LOG2E 1.4426950408889634f

// ---------------------------------------------------------------------------
// 16-lane row sum via DPP (VALU pipe only).
// ---------------------------------------------------------------------------
template <int CTRL>
__device__ __forceinline__ float dpp_add(float v) {
    int s = __builtin_bit_cast(int, v);
    int t = __builtin_amdgcn_update_dpp(0, s, CTRL, 0xF, 0xF, true);
    return v + __builtin_bit_cast(float, t);
}
__device__ __forceinline__ float row_sum16(float v) {
    v = dpp_add<0xB1>(v);   // xor1
    v = dpp_add<0x4E>(v);   // xor2
    v = dpp_add<0x124>(v);  // row_ror:4
    v = dpp_add<0x128>(v);  // row_ror:8
    return v;
}

// 8-element f16 dot with fp32 accumulate: 4 x v_dot2_f32_f16.
__device__ __forceinline__ float dot8(h8 w, h8 x) {
    h2 w0 = __builtin_shufflevector(w, w, 0, 1), w1 = __builtin_shufflevector(w, w, 2, 3);
    h2 w2 = __builtin_shufflevector(w, w, 4, 5), w3 = __builtin_shufflevector(w, w, 6, 7);
    h2 x0 = __builtin_shufflevector(x, x, 0, 1), x1 = __builtin_shufflevector(x, x, 2, 3);
    h2 x2 = __builtin_shufflevector(x, x, 4, 5), x3 = __builtin_shufflevector(x, x, 6, 7);
    float acc = __builtin_amdgcn_fdot2(w0, x0, 0.0f, false);
    acc = __builtin_amdgcn_fdot2(w1, x1, acc, false);
    acc = __builtin_amdgcn_fdot2(w2, x2, acc, false);
    acc = __builtin_amdgcn_fdot2(w3, x3, acc, false);
    return acc;
}

// ---------------------------------------------------------------------------
// prep (vectorized): W,X fp32 -> f16; zero S0/S1/S2.
// ---------------------------------------------------------------------------
__global__ __launch_bounds__(256) void prep_kernel(
    const float* __restrict__ X, const float* __restrict__ W,
    _Float16* __restrict__ Xh, _Float16* __restrict__ Wh,
    float* __restrict__ S)   // 3*NS floats
{
    const int g = blockIdx.x * 256 + threadIdx.x;
    const int stride = gridDim.x * 256;
    typedef _Float16 h4 __attribute__((ext_vector_type(4)));
    for (int k = g; k < NW / 4; k += stride) {
        const float4 f = ((const float4*)W)[k];
        h4 o = { (_Float16)f.x, (_Float16)f.y, (_Float16)f.z, (_Float16)f.w };
        ((h4*)Wh)[k] = o;
    }
    for (int k = g; k < NX / 4; k += stride) {
        const float4 f = ((const float4*)X)[k];
        h4 o = { (_Float16)f.x, (_Float16)f.y, (_Float16)f.z, (_Float16)f.w };
        ((h4*)Xh)[k] = o;
    }
    const float4 z = {0.f, 0.f, 0.f, 0.f};
    for (int k = g; k < 3 * NS / 4; k += stride) ((float4*)S)[k] = z;
}

// ---------------------------------------------------------------------------
// Fused routing pass, LDS-fed. Block = 256 threads = 16 b-groups x 16 p-lanes.
// Prologue: stage the block's W-tile (j=10 x i=8 x p=16 x q=8 f16 = 20 KB)
// and x-tile (16b x 8i x 8q f16 = 2 KB) into LDS. W reads in the hot loop are
// ds_read_b128: p-lanes hit 256 contiguous B (2-way bank alias, free) and all
// b-groups broadcast the same addresses. No global-load latency in the loop,
// no VGPR in-flight buffers -> no spills (R9 post-mortem).
// vv[j] = squash(Sprev)[p]*log2e inline via DPP; R==1,it==0 persists v0;
// R==2 adds v0 (cumulative logits, no BL tensor). R==0: c uniform.
// ---------------------------------------------------------------------------
template <int R>
__global__ __launch_bounds__(256, 4) void pass_kernel(
    const _Float16* __restrict__ Xh,  // [B][I][Q] f16
    const _Float16* __restrict__ Wh,  // [J][I][P][Q] f16
    const float* __restrict__ Sprev,  // [B][J][P] (R>0)
    float* __restrict__ V0,           // [B][J][P] v0 (R1 writes it==0, R2 reads)
    float* __restrict__ Sout)         // [B][J][P] pre-zeroed accumulator
{
    __shared__ _Float16 ws[JJ * WTILE];  // 20 KB
    __shared__ _Float16 xs[BT * XRH];    // 2.25 KB

    const int bt = blockIdx.x & (NBT - 1);
    const int it = blockIdx.x >> 4;
    const int b0 = bt * BT;
    const int i0 = it * IT;
    const int tid = threadIdx.x;

    // ---- stage W tile: 1280 h8 chunks, 5 per thread (coalesced 16B/lane)
    {
        const size_t jstride = (size_t)II * PP * QQ;
        const _Float16* wsrc = Wh + (size_t)i0 * PP * QQ;
#pragma unroll
        for (int k = 0; k < 5; ++k) {
            const int c = tid + k * 256;   // 0..1279
            const int j = c >> 7;          // 128 h8 chunks per j
            const int r = c & 127;
            *(h8*)(ws + j * WTILE + r * 8) = *(const h8*)(wsrc + j * jstride + r * 8);
        }
        // ---- stage x tile: 128 h8 chunks (first 128 threads)
        if (tid < 128) {
            const int xb = tid >> 3;
            const int xr = tid & 7;
            *(h8*)(xs + xb * XRH + xr * 8) =
                *(const h8*)(Xh + ((size_t)(b0 + xb) * II + i0) * QQ + xr * 8);
        }
    }
    __syncthreads();

    const int b_l = tid >> 4;
    const int p   = tid & 15;
    const int b   = b0 + b_l;

    // inline squash of Sprev -> vv (pre-scaled by log2e)
    float vv[JJ];
    if (R > 0) {
#pragma unroll
        for (int j = 0; j < JJ; ++j) {
            const float sp = Sprev[((size_t)b * JJ + j) * PP + p];
            const float n2 = row_sum16(sp * sp);
            const float scale = n2 * __builtin_amdgcn_rcpf(1.0f + n2)
                                   * __builtin_amdgcn_rsqf(n2 + 1e-7f);
            float v = sp * scale;
            if (R == 1) {
                if (it == 0) V0[((size_t)b * JJ + j) * PP + p] = v;
            } else {
                v += V0[((size_t)b * JJ + j) * PP + p];
            }
            vv[j] = v * LOG2E;
        }
    }

    float sacc[JJ];
#pragma unroll
    for (int j = 0; j < JJ; ++j) sacc[j] = 0.0f;

#pragma unroll
    for (int i = 0; i < IT; ++i) {
        const h8 x8 = *(const h8*)(xs + b_l * XRH + i * QQ);

        float h[JJ];
#pragma unroll
        for (int j = 0; j < JJ; ++j)
            h[j] = dot8(*(const h8*)(ws + j * WTILE + (i * PP + p) * QQ), x8);

        if (R == 0) {
#pragma unroll
            for (int j = 0; j < JJ; ++j) sacc[j] += h[j];
        } else {
            float e[JJ];
#pragma unroll
            for (int j = 0; j < JJ; ++j) {
                const float bj = row_sum16(vv[j] * h[j]);
                e[j] = exp2f(bj);
            }
            // tree sum (depth 4)
            float s01 = e[0] + e[1], s23 = e[2] + e[3], s45 = e[4] + e[5],
                  s67 = e[6] + e[7], s89 = e[8] + e[9];
            float t0 = s01 + s23, t1 = s45 + s67;
            const float sum = (t0 + t1) + s89;
            const float inv = __builtin_amdgcn_rcpf(sum);
#pragma unroll
            for (int j = 0; j < JJ; ++j) sacc[j] += (e[j] * inv) * h[j];
        }
    }

#pragma unroll
    for (int j = 0; j < JJ; ++j)
        atomicAdd(&Sout[((size_t)b * JJ + j) * PP + p],
                  (R == 0) ? 0.1f * sacc[j] : sacc[j]);
}

// ---------------------------------------------------------------------------
// final output squash (fp32 precise)
// ---------------------------------------------------------------------------
__global__ __launch_bounds__(256) void squash_out_kernel(const float* __restrict__ S,
                                                         float* __restrict__ V)
{
    const int idx = blockIdx.x * blockDim.x + threadIdx.x;  // (b*J + j)
    if (idx >= BB * JJ) return;
    const float4* sp = (const float4*)(S + idx * PP);
    float4 a = sp[0], b4 = sp[1], c4 = sp[2], d4 = sp[3];
    float s2 = a.x * a.x + a.y * a.y + a.z * a.z + a.w * a.w +
               b4.x * b4.x + b4.y * b4.y + b4.z * b4.z + b4.w * b4.w +
               c4.x * c4.x + c4.y * c4.y + c4.z * c4.z + c4.w * c4.w +
               d4.x * d4.x + d4.y * d4.y + d4.z * d4.z + d4.w * d4.w;
    const float scale = s2 / (1.0f + s2) / sqrtf(s2 + 1e-7f);
    a.x *= scale; a.y *= scale; a.z *= scale; a.w *= scale;
    b4.x *= scale; b4.y *= scale; b4.z *= scale; b4.w *= scale;
    c4.x *= scale; c4.y *= scale; c4.z *= scale; c4.w *= scale;
    d4.x *= scale; d4.y *= scale; d4.z *= scale; d4.w *= scale;
    float4* vp = (float4*)(V + idx * PP);
    vp[0] = a; vp[1] = b4; vp[2] = c4; vp[3] = d4;
}

extern "C" void kernel_launch(void* const* d_in, const int* in_sizes, int n_in,
                              void* d_out, int out_size, void* d_ws, size_t ws_size,
                              hipStream_t stream)
{
    const float* X = (const float*)d_in[0];  // [256][1152][8]
    const float* W = (const float*)d_in[1];  // [10][1152][16][8]
    float* out = (float*)d_out;              // [256][10][16]

    _Float16* Xh = (_Float16*)d_ws;          // NX halfs
    _Float16* Wh = Xh + NX;                  // NW halfs
    float* S0 = (float*)(Wh + NW);           // NS floats
    float* S1 = S0 + NS;
    float* S2 = S1 + NS;
    float* v0 = S2 + NS;                     // NS floats; total ~8.3 MB

    const int grid = NBT * NIT;  // 2304 blocks of 256 threads

    prep_kernel<<<1024, 256, 0, stream>>>(X, W, Xh, Wh, S0);
    pass_kernel<0><<<grid, 256, 0, stream>>>(Xh, Wh, nullptr, nullptr, S0);
    pass_kernel<1><<<grid, 256, 0, stream>>>(Xh, Wh, S0, v0, S1);
    pass_kernel<2><<<grid, 256, 0, stream>>>(Xh, Wh, S1, v0, S2);
    squash_out_kernel<<<10, 256, 0, stream>>>(S2, out);
}